// Round 5
// baseline (140.683 us; speedup 1.0000x reference)
//
#include <hip/hip_runtime.h>
#include <stdint.h>

// Problem constants (B=2, C=512, H=128, W=256, G=8, maxdisp=48)
#define NB 2
#define NG 8
#define CG 64
#define HH 128
#define WW 256
#define ND 48
#define CHUNK 8          // channels staged per round
#define NCH (CG / CHUNK) // 8 rounds
#define TPB 256          // 4 waves; wave wv owns d in [12wv, 12wv+12)
#define DT 12
#define ROWF 320         // stgt row: floats [0,16) unused, [16,64) zero pad, [64,320) = w 0..255

// XOR swizzle on float4-slot index (involution within aligned 8-slot blocks).
__device__ __forceinline__ int swz8(int q) { return q ^ ((q >> 3) & 7); }

// Async global->LDS, 16B per lane. LDS dest = wave-uniform base + lane*16 (HW).
__device__ __forceinline__ void gload_lds16(const float* g, float* l) {
    __builtin_amdgcn_global_load_lds(
        (__attribute__((address_space(1))) void*)g,
        (__attribute__((address_space(3))) void*)l, 16, 0, 0);
}

__global__ __launch_bounds__(TPB, 4)
void gwc_kernel(const float* __restrict__ ref, const float* __restrict__ tgt,
                float* __restrict__ out) {
    __shared__ float sB[2][CHUNK][ROWF];   // 20.5 KB, double-buffered tgt

    const int tid  = threadIdx.x;
    const int lane = tid & 63;
    const int wv   = tid >> 6;             // 0..3
    const int d0   = DT * wv;

    const int blk  = blockIdx.x;           // b*G*H + g*H + h
    const int hrow = blk % HH;
    const int bg   = blk / HH;

    // Zero the pad (floats [16,64) of every row, both buffers) once.
    for (int i = tid; i < 2 * CHUNK * 48; i += TPB) {
        const int b   = i / (CHUNK * 48);
        const int rem = i % (CHUNK * 48);
        sB[b][rem / 48][16 + rem % 48] = 0.0f;
    }

    const size_t rowstride = (size_t)HH * WW;
    const float* refbase = ref + ((size_t)bg * CG * HH + hrow) * WW;
    const float* tgtbase = tgt + ((size_t)bg * CG * HH + hrow) * WW;

    // Staging: lane supplies PRE-SWIZZLED global address; LDS written linearly.
    // Physical data-slot p then holds logical slot swz8(p) (involution).
    const int goff = 4 * swz8(lane);

    // tv read offsets: logical data-slots x..x+3, x = lane - 3*wv - 3.
    // Negative x -> zero-pad region (stored unswizzled at floats 64+4x).
    int toff[4];
    #pragma unroll
    for (int k = 0; k < 4; ++k) {
        const int x = lane - 3 * wv - 3 + k;
        toff[k] = (x >= 0) ? 4 * (16 + swz8(x)) : 4 * (16 + x);
    }

    float acc[DT][4];
    #pragma unroll
    for (int i = 0; i < DT; ++i)
        #pragma unroll
        for (int j = 0; j < 4; ++j) acc[i][j] = 0.0f;

    // ---- prologue: stage chunk 0 into buffer 0 (wave wv -> rows 2wv, 2wv+1) ----
    #pragma unroll
    for (int j = 0; j < 2; ++j) {
        const int r = 2 * wv + j;
        gload_lds16(tgtbase + (size_t)r * rowstride + goff, &sB[0][r][64]);
    }

    int cur = 0;
    for (int ch = 0; ch < NCH; ++ch) {
        __syncthreads();  // drains vmcnt: buf[cur] ready; buf[cur^1] free
        if (ch + 1 < NCH) {
            // async prefetch of next chunk -> flies under this round's compute
            #pragma unroll
            for (int j = 0; j < 2; ++j) {
                const int r = 2 * wv + j;
                gload_lds16(tgtbase + (size_t)((ch + 1) * CHUNK + r) * rowstride + goff,
                            &sB[cur ^ 1][r][64]);
            }
        }
        // ---- compute chunk ch: tgt from LDS, ref straight from global (L1/L2) ----
        #pragma unroll
        for (int c = 0; c < CHUNK; ++c) {
            float rv[4];
            *(float4*)rv =
                *(const float4*)(refbase + (size_t)(ch * CHUNK + c) * rowstride + 4 * lane);
            float tv[16];
            #pragma unroll
            for (int k = 0; k < 4; ++k)
                *(float4*)&tv[4 * k] = *(const float4*)&sB[cur][c][toff[k]];
            #pragma unroll
            for (int dd = 0; dd < DT; ++dd)
                #pragma unroll
                for (int ww = 0; ww < 4; ++ww)
                    acc[dd][ww] += rv[ww] * tv[12 + ww - dd];  // static idx in [1,15]
        }
        cur ^= 1;
    }

    // ---- epilogue: out[((bg*ND + d)*HH + hrow)*WW + 4*lane] ----
    float* obase = out + ((size_t)bg * ND) * rowstride + (size_t)hrow * WW + 4 * lane;
    #pragma unroll
    for (int dd = 0; dd < DT; ++dd)
        *(float4*)(obase + (size_t)(d0 + dd) * rowstride) =
            make_float4(acc[dd][0], acc[dd][1], acc[dd][2], acc[dd][3]);
}

extern "C" void kernel_launch(void* const* d_in, const int* in_sizes, int n_in,
                              void* d_out, int out_size, void* d_ws, size_t ws_size,
                              hipStream_t stream) {
    const float* ref = (const float*)d_in[0];
    const float* tgt = (const float*)d_in[1];
    float* out = (float*)d_out;
    const int grid = NB * NG * HH;   // 2048 blocks, one per (b, g, h)
    gwc_kernel<<<dim3(grid), dim3(TPB), 0, stream>>>(ref, tgt, out);
}